// Round 4
// baseline (67155.701 us; speedup 1.0000x reference)
//
#include <hip/hip_runtime.h>
#include <stdint.h>

#define DEV static __device__ __forceinline__

namespace {
constexpr int Bx = 16, ENCx = 512, DECx = 800, Dx = 256, Hx = 1024;
constexpr int NBLK = 256, NTHR = 512;

// ---- workspace float offsets ----
constexpr int WS_HBUF = 0;                     // 2 * B*H (double-buffered h)
constexpr int WS_CTX  = WS_HBUF + 2*Bx*Hx;     // B*D
constexpr int WS_NCTX = WS_CTX  + Bx*Dx;       // B*D
constexpr int WS_X1   = WS_NCTX + Bx*Dx;       // B*D
constexpr int WS_AL   = WS_X1   + Bx*Dx;       // B*ENC
constexpr int WS_FEND = WS_AL   + Bx*ENCx;
// ---- int offsets (relative to wsf + WS_FEND) ----
constexpr int IW_F1   = 0;                     // flag1[DEC]    : x1 done (count to 32)
constexpr int IW_F2   = IW_F1 + DECx;          // flag2[DEC*16] : align[b] done
constexpr int IW_SLOT = ((IW_F2 + DECx*16 + 63)/64)*64;  // 256 barrier slots
constexpr int IW_GEN  = IW_SLOT + 256 + 64;    // 8 replicated gen words, stride 32
constexpr int IW_END  = IW_GEN + 256;
constexpr size_t CTXOUT = (size_t)Bx*DECx*Dx;  // weights output offset

// ---- dynamic LDS float offsets ----
constexpr int LH_STR = 1028;                   // padded h stride (2-way banks = free)
constexpr int CT_STR = 260;                    // padded ctx stride in region 2
constexpr int LW_H   = 0;                      // 16*1028 = 16448 (h; reused ctx|nctx)
constexpr int LW_WHH = LW_H + 16*LH_STR;       // 16384: Whh rows [16][1024]
constexpr int LW_TS  = LW_WHH + 16384;         // type-specific union (7192 floats)
// head view of union:
constexpr int TS_WLT = 0;                      // wlinT [256][24]
constexpr int TS_BLN = 6144;                   // blin [24]
constexpr int TS_X1L = 6168;                   // x1 stage [256]
constexpr int TS_X2P = 6424;                   // x2 partials [512]
constexpr int TS_X2L = 6936;                   // x2 tanh [256]
// slice view of union:
constexpr int TS_CPN = 0;                      // cpn [2][32][16]
constexpr int TS_ALB = 1024;                   // albl [512]
constexpr int LDS_DYN_F = LW_TS + 7192;        // 40024 floats
constexpr size_t SMEM_BYTES = (size_t)LDS_DYN_F * 4;   // 160096 B
}

DEV float frcp(float x){ return __builtin_amdgcn_rcpf(x); }
DEV float sigm(float x){ return frcp(1.0f + __expf(-x)); }
DEV float ftanh(float x){
  x = fminf(fmaxf(x, -15.0f), 15.0f);
  float e = __expf(2.0f*x);
  return (e - 1.0f) * frcp(e + 1.0f);
}
DEV float wred16(float v){
  v += __shfl_xor(v, 1); v += __shfl_xor(v, 2);
  v += __shfl_xor(v, 4); v += __shfl_xor(v, 8);
  return v;
}
DEV int   ld_rlx(const int* p){ return __hip_atomic_load(p, __ATOMIC_RELAXED, __HIP_MEMORY_SCOPE_AGENT); }
DEV void  st_rlx(int* p, int v){ __hip_atomic_store(p, v, __ATOMIC_RELAXED, __HIP_MEMORY_SCOPE_AGENT); }
DEV float ldf_c(const float* p){ return __hip_atomic_load(p, __ATOMIC_RELAXED, __HIP_MEMORY_SCOPE_AGENT); }
DEV void  stf_c(float* p, float v){ __hip_atomic_store(p, v, __ATOMIC_RELAXED, __HIP_MEMORY_SCOPE_AGENT); }
DEV float2 ldf2_c(const float* p){
  unsigned long long u = __hip_atomic_load((const unsigned long long*)p,
                                           __ATOMIC_RELAXED, __HIP_MEMORY_SCOPE_AGENT);
  return __builtin_bit_cast(float2, u);
}
DEV void cbar(){ asm volatile("" ::: "memory"); }

// busy-wait delay: ~100 cycles of dependent VALU (keeps clocks up, throttles poll rate)
DEV void spin_delay(){
  float x = 1.0f;
  #pragma unroll
  for (int i = 0; i < 24; ++i) x = fmaf(x, 1.0000001f, 1e-9f);
  asm volatile("" :: "v"(x));
}

DEV void flag_wait(int* p, int target){
  if (threadIdx.x == 0){
    while (ld_rlx(p) < target) spin_delay();
  }
  __syncthreads();
  cbar();
}

// fence-free slot barrier with 8x-replicated generation broadcast
DEV void gridbar(int* slots, int* genp, unsigned &gen){
  const int next = (int)(gen + 1u);
  __syncthreads();                       // drains vmcnt: sc1 stores at coherence point
  if (threadIdx.x == 0) st_rlx(slots + blockIdx.x, next);
  if (blockIdx.x == 0 && threadIdx.x < 64){
    int* my = slots + threadIdx.x*4;
    for (;;){
      bool ok = (ld_rlx(my+0) >= next) & (ld_rlx(my+1) >= next) &
                (ld_rlx(my+2) >= next) & (ld_rlx(my+3) >= next);
      if (__ballot(ok) == ~0ull) break;
      spin_delay();
    }
    if (threadIdx.x < 8) st_rlx(genp + threadIdx.x*32, next);
  }
  if (threadIdx.x == 0){
    int* g = genp + (blockIdx.x & 7)*32;
    while (ld_rlx(g) < next) spin_delay();
  }
  __syncthreads();
  cbar();
  gen = (unsigned)next;
}

DEV void gchunk(float (&acc)[2][4], float4 wa, float4 wb, const float* xlane, size_t xstride, int b4){
  #pragma unroll
  for (int bi = 0; bi < 4; ++bi){
    float4 xv = *reinterpret_cast<const float4*>(xlane + (size_t)(b4*4 + bi)*xstride);
    acc[0][bi] = fmaf(wa.x,xv.x, fmaf(wa.y,xv.y, fmaf(wa.z,xv.z, fmaf(wa.w,xv.w, acc[0][bi]))));
    acc[1][bi] = fmaf(wb.x,xv.x, fmaf(wb.y,xv.y, fmaf(wb.z,xv.z, fmaf(wb.w,xv.w, acc[1][bi]))));
  }
}

extern "C" __global__ void gmm_init(float* wsf){
  int* wsi = (int*)(wsf + WS_FEND);
  int idx = blockIdx.x*blockDim.x + threadIdx.x;
  for (int k = idx; k < IW_END; k += gridDim.x*blockDim.x) wsi[k] = 0;
}

extern "C" __global__ void __launch_bounds__(NTHR, 1) gmm_main(
    const float* __restrict__ enc, const float* __restrict__ mel,
    const int* __restrict__ outlen, const int* __restrict__ condlen,
    const float* __restrict__ Wih, const float* __restrict__ Whh,
    const float* __restrict__ bih, const float* __restrict__ bhh,
    const float* __restrict__ W1,  const float* __restrict__ b1v,
    const float* __restrict__ W2,  const float* __restrict__ Wlin,
    const float* __restrict__ blin,
    float* __restrict__ out, float* __restrict__ wsf)
{
  const int bk = blockIdx.x, tid = threadIdx.x;
  const int lane = tid & 63;
  const int klane4 = (tid & 15) * 4;
  const int b4 = (tid >> 4) & 3;
  const int wid = tid >> 6;

  int* wsi   = (int*)(wsf + WS_FEND);
  int* flag1 = wsi + IW_F1;
  int* flag2 = wsi + IW_F2;
  int* slots = wsi + IW_SLOT;
  int* genp  = wsi + IW_GEN;
  float* hb0    = wsf + WS_HBUF;
  float* ctxws  = wsf + WS_CTX;
  float* nctxws = wsf + WS_NCTX;
  float* x1ws   = wsf + WS_X1;
  float* alws   = wsf + WS_AL;

  extern __shared__ float lds[];
  float* lh   = lds + LW_H;
  float* lwhh = lds + LW_WHH;
  float* lts  = lds + LW_TS;

  __shared__ float g_lds[256];
  __shared__ float bsum[16];
  __shared__ float cl[64];
  __shared__ float outl[32];
  __shared__ float mixw[8], mixlc[8], mixis[8];
  __shared__ float locl[8];
  __shared__ int   s_cond, s_olen;

  const int jidx0 = 2*wid;
  const int j0 = (jidx0 >> 2)*1024 + bk*4 + (jidx0 & 3);
  const int j1 = ((jidx0+1) >> 2)*1024 + bk*4 + ((jidx0+1) & 3);
  const float* WihR0 = Wih + (size_t)j0*768;   // read-only -> L2-resident
  const float* WihR1 = Wih + (size_t)j1*768;

  const bool is_x1   = (bk < 32);
  const bool is_head = (bk >= 32 && bk < 48);  // one block per batch
  const int  hbb     = bk - 32;

  // slice mapping for non-head blocks: idx 0..239 -> 256 slices
  int sl_cb = 0, sl_dc0 = 0, sl_n = 0;
  if (!is_head){
    int idx = (bk < 32) ? bk : (bk - 16);
    if (idx < 16){ sl_cb = idx; sl_dc0 = 14; sl_n = 2; }
    else { int j = idx - 16; sl_cb = j / 14; sl_dc0 = j % 14; sl_n = 1; }
  }

  // ---------------- one-time staging ----------------
  #pragma unroll
  for (int jj = jidx0; jj <= jidx0 + 1; ++jj){
    const int gj = (jj >> 2)*1024 + bk*4 + (jj & 3);
    float4* dst = (float4*)(lwhh + jj*1024);
    const float4* s = (const float4*)(Whh + (size_t)gj*1024);
    for (int i = lane; i < 256; i += 64) dst[i] = s[i];
  }
  if (tid < 16){
    int g = tid >> 2, ul = tid & 3, u = bk*4 + ul;
    bsum[tid] = bih[g*1024 + u] + bhh[g*1024 + u];
  }
  float4 w2r[32];          // head: W2[r = tid>>1, (tid&1)*128 .. +128] in registers
  if (is_head){
    for (int i = tid; i < 6144; i += NTHR){
      int k = i >> 5;           // 0..191  (wait: 6144/32=192) -- use div by 24 layout instead
      (void)k;
    }
    // wlinT[k*24 + r] = Wlin[r][k], k<256, r<24
    for (int i = tid; i < 6144; i += NTHR){
      int k = i / 24, r = i % 24;
      lts[TS_WLT + i] = Wlin[(size_t)r*256 + k];
    }
    if (tid < 24) lts[TS_BLN + tid] = blin[tid];
    if (tid == 0){ s_cond = condlen[hbb]; s_olen = outlen[hbb]; }
    if (tid < 8) locl[tid] = -0.1f;
    {
      int r = tid >> 1, hf = tid & 1;
      const float* w2row = W2 + (size_t)r*256 + hf*128;
      #pragma unroll
      for (int i = 0; i < 32; ++i) w2r[i] = *reinterpret_cast<const float4*>(w2row + i*4);
    }
  }
  __syncthreads();

  auto ctx_slice = [&](int cb, int dc, int t){
    int d0 = dc * 16;
    int dl = tid & 15, eg = tid >> 4;
    int d = d0 + dl;
    const float* encb = enc + (size_t)cb*ENCx*Dx;
    const float* albl = lts + TS_ALB;
    float* cpn = lts + TS_CPN;
    float ca = 0.f, na = 0.f;
    #pragma unroll
    for (int i = 0; i < 16; ++i){
      int e = eg*16 + i;
      float av = albl[e];
      float nv = albl[(e + 511) & 511];
      float ev = encb[(size_t)e*256 + d];
      ca = fmaf(av, ev, ca);
      na = fmaf(nv, ev, na);
    }
    cpn[0*512 + eg*16 + dl] = ca;
    cpn[1*512 + eg*16 + dl] = na;
    __syncthreads();
    if (tid < 32){
      int z = tid >> 4, dd = tid & 15;
      float sum = 0.f;
      #pragma unroll
      for (int g2 = 0; g2 < 32; ++g2) sum += cpn[z*512 + g2*16 + dd];
      if (z == 0){
        stf_c(ctxws + cb*256 + d0 + dd, sum);
        out[(size_t)cb*((size_t)DECx*Dx) + (size_t)t*Dx + d0 + dd] = sum;
      } else {
        stf_c(nctxws + cb*256 + d0 + dd, sum);
      }
    }
    __syncthreads();
  };

  unsigned gen = 0;

  // ---------------- prologue: gates t=0 (q=[mel0, 0, enc[:,0,:]], h=0, c=0) ----------------
  {
    float acc[2][4] = {{0,0,0,0},{0,0,0,0}};
    #pragma unroll
    for (int it = 0; it < 4; ++it){
      int k = it*64 + klane4;
      gchunk(acc, *(const float4*)(WihR0 + k), *(const float4*)(WihR1 + k),
             mel + k, (size_t)DECx*Dx, b4);
    }
    #pragma unroll
    for (int it = 0; it < 4; ++it){
      int k = it*64 + klane4;
      gchunk(acc, *(const float4*)(WihR0 + 512 + k), *(const float4*)(WihR1 + 512 + k),
             enc + k, (size_t)ENCx*Dx, b4);
    }
    #pragma unroll
    for (int jj = 0; jj < 2; ++jj)
      #pragma unroll
      for (int bi = 0; bi < 4; ++bi){
        float v = wred16(acc[jj][bi]);
        if ((tid & 15) == 0) g_lds[(jidx0 + jj)*16 + b4*4 + bi] = v;
      }
    __syncthreads();
    if (tid < 64){
      int b = tid & 15, ul = tid >> 4, u = bk*4 + ul;
      float gi = g_lds[( 0 + ul)*16 + b] + bsum[ul];
      float gg = g_lds[( 8 + ul)*16 + b] + bsum[8 + ul];
      float go = g_lds[(12 + ul)*16 + b] + bsum[12 + ul];
      float c2 = sigm(gi) * ftanh(gg);
      float h2 = sigm(go) * ftanh(c2);
      cl[b*4 + ul] = c2;
      stf_c(hb0 + b*1024 + u, h2);
    }
  }
  gridbar(slots, genp, gen);

  // ---------------- main loop ----------------
  for (int t = 0; t < DECx; ++t){
    // ---- stage h_t -> LDS (padded stride), block-staggered start to spread L3 demand
    {
      const float* hsrc = hb0 + (t & 1)*Bx*Hx;
      #pragma unroll 4
      for (int i = tid; i < 8192; i += NTHR){
        int j = (i + bk*64) & 8191;
        int b = j >> 9, k2 = j & 511;
        *reinterpret_cast<float2*>(lh + b*LH_STR + 2*k2) = ldf2_c(hsrc + 2*j);
      }
    }
    __syncthreads();

    // ---- x1 engines (h from LDS, W1 from L2)
    if (is_x1){
      int d = bk*8 + wid;
      const float* W1r = W1 + (size_t)d*1024;
      float a4[4] = {0,0,0,0};
      #pragma unroll 4
      for (int it = 0; it < 16; ++it){
        int k = it*64 + klane4;
        float4 wq = *(const float4*)(W1r + k);
        #pragma unroll
        for (int bi = 0; bi < 4; ++bi){
          float4 xv = *(const float4*)(lh + (size_t)(b4*4 + bi)*LH_STR + k);
          a4[bi] = fmaf(wq.x,xv.x, fmaf(wq.y,xv.y, fmaf(wq.z,xv.z, fmaf(wq.w,xv.w, a4[bi]))));
        }
      }
      #pragma unroll
      for (int bi = 0; bi < 4; ++bi){
        float v = wred16(a4[bi]);
        if ((tid & 15) == 0){
          v += b1v[d];
          v = (v >= 0.f) ? v : 0.1f*v;
          stf_c(x1ws + (b4*4 + bi)*256 + d, v);
        }
      }
      __syncthreads();
      if (tid == 0)
        __hip_atomic_fetch_add(flag1 + t, 1, __ATOMIC_RELAXED, __HIP_MEMORY_SCOPE_AGENT);
    }

    // ---- head engines (one block per batch): x2 -> out -> softmax -> align
    if (is_head){
      flag_wait(flag1 + t, 32);
      if (tid < 256) lts[TS_X1L + tid] = ldf_c(x1ws + hbb*256 + tid);
      __syncthreads();
      {
        int hf = tid & 1;
        const float* x1b = lts + TS_X1L + hf*128;
        float a = 0.f;
        #pragma unroll
        for (int i = 0; i < 32; ++i){
          float4 xv = *(const float4*)(x1b + i*4);
          a = fmaf(w2r[i].x,xv.x, fmaf(w2r[i].y,xv.y, fmaf(w2r[i].z,xv.z, fmaf(w2r[i].w,xv.w, a))));
        }
        lts[TS_X2P + tid] = a;
      }
      __syncthreads();
      if (tid < 256) lts[TS_X2L + tid] = ftanh(lts[TS_X2P + 2*tid] + lts[TS_X2P + 2*tid + 1]);
      __syncthreads();
      if (tid < 24){
        float s = lts[TS_BLN + tid];
        #pragma unroll 8
        for (int k = 0; k < 256; ++k) s = fmaf(lts[TS_X2L + k], lts[TS_WLT + k*24 + tid], s);
        outl[tid] = s;
      }
      __syncthreads();
      if (tid == 0){
        float w8[8]; float mx = -1e30f;
        #pragma unroll
        for (int m = 0; m < 8; ++m){ w8[m] = outl[m]; mx = fmaxf(mx, w8[m]); }
        float sum = 0.f;
        #pragma unroll
        for (int m = 0; m < 8; ++m){ w8[m] = __expf(w8[m] - mx); sum += w8[m]; }
        float inv = frcp(sum);
        float cm1 = (float)s_cond - 1.0f;
        #pragma unroll
        for (int m = 0; m < 8; ++m){
          mixw[m] = w8[m] * inv;
          float dl = sigm(outl[8 + m]) + 0.005f;
          float lc = locl[m] + dl;
          mixlc[m] = lc;
          locl[m]  = fminf(lc, cm1);
          mixis[m] = 1.0f + __expf(-outl[16 + m]);
        }
      }
      __syncthreads();
      {
        float e = (float)tid;
        float a = 0.f;
        #pragma unroll
        for (int m = 0; m < 8; ++m){
          float df = mixlc[m] - e;
          a += (ftanh((df + 0.5f)*mixis[m]) - ftanh((df - 0.5f)*mixis[m])) * mixw[m];
        }
        a *= 0.5f;
        bool valid = (tid < s_cond) && (t < s_olen);
        if (!valid) a = 0.f;
        stf_c(alws + hbb*512 + tid, a);
        out[CTXOUT + (size_t)hbb*((size_t)DECx*ENCx) + (size_t)t*ENCx + tid] = a;
      }
      __syncthreads();                     // vmcnt(0): align at coherence point
      if (tid == 0) st_rlx(flag2 + t*16 + hbb, 1);
    }

    // ---- region 1: gate partial for t+1 (Wih-mel from L2; Whh+h from LDS)
    float acc[2][4] = {{0,0,0,0},{0,0,0,0}};
    if (t < DECx - 1){
      const int tt = t + 1;
      #pragma unroll
      for (int it = 0; it < 4; ++it){
        int k = it*64 + klane4;
        gchunk(acc, *(const float4*)(WihR0 + k), *(const float4*)(WihR1 + k),
               mel + (size_t)tt*Dx + k, (size_t)DECx*Dx, b4);
      }
      #pragma unroll 4
      for (int it = 0; it < 16; ++it){
        int k = it*64 + klane4;
        gchunk(acc, *(const float4*)(lwhh + jidx0*1024 + k), *(const float4*)(lwhh + (jidx0+1)*1024 + k),
               lh + k, LH_STR, b4);
      }
    }

    // ---- ctx duty (head exempt)
    if (!is_head){
      flag_wait(flag2 + t*16 + sl_cb, 1);
      lts[TS_ALB + tid] = ldf_c(alws + sl_cb*512 + tid);
      __syncthreads();
      ctx_slice(sl_cb, sl_dc0, t);
      if (sl_n == 2) ctx_slice(sl_cb, sl_dc0 + 1, t);
    }

    gridbar(slots, genp, gen);   // barrier A: ctx/nctx published

    // ---- region 2: ctx/nctx gate part + LSTM cell -> h_{t+1}
    if (t < DECx - 1){
      // stage ctx|nctx into lh (padded stride CT_STR)
      #pragma unroll 2
      for (int i = tid; i < 2048; i += NTHR){
        int j = (i + bk*32) & 2047;
        int b = j >> 7, k2 = j & 127;
        *reinterpret_cast<float2*>(lh + b*CT_STR + 2*k2) = ldf2_c(ctxws + 2*j);
      }
      #pragma unroll 2
      for (int i = tid; i < 2048; i += NTHR){
        int j = (i + bk*32) & 2047;
        int b = j >> 7, k2 = j & 127;
        *reinterpret_cast<float2*>(lh + (16 + b)*CT_STR + 2*k2) = ldf2_c(nctxws + 2*j);
      }
      __syncthreads();
      #pragma unroll
      for (int it = 0; it < 4; ++it){
        int k = it*64 + klane4;
        gchunk(acc, *(const float4*)(WihR0 + 256 + k), *(const float4*)(WihR1 + 256 + k),
               lh + k, CT_STR, b4);
      }
      #pragma unroll
      for (int it = 0; it < 4; ++it){
        int k = it*64 + klane4;
        gchunk(acc, *(const float4*)(WihR0 + 512 + k), *(const float4*)(WihR1 + 512 + k),
               lh + 16*CT_STR + k, CT_STR, b4);
      }
      #pragma unroll
      for (int jj = 0; jj < 2; ++jj)
        #pragma unroll
        for (int bi = 0; bi < 4; ++bi){
          float v = wred16(acc[jj][bi]);
          if ((tid & 15) == 0) g_lds[(jidx0 + jj)*16 + b4*4 + bi] = v;
        }
      __syncthreads();
      if (tid < 64){
        int b = tid & 15, ul = tid >> 4, u = bk*4 + ul;
        float gi = g_lds[( 0 + ul)*16 + b] + bsum[ul];
        float gf = g_lds[( 4 + ul)*16 + b] + bsum[4 + ul];
        float gg = g_lds[( 8 + ul)*16 + b] + bsum[8 + ul];
        float go = g_lds[(12 + ul)*16 + b] + bsum[12 + ul];
        float co = cl[b*4 + ul];
        float c2 = sigm(gf)*co + sigm(gi)*ftanh(gg);
        float h2 = sigm(go)*ftanh(c2);
        cl[b*4 + ul] = c2;
        stf_c(hb0 + ((t + 1) & 1)*Bx*Hx + b*1024 + u, h2);
      }
    }

    gridbar(slots, genp, gen);   // barrier B: h_{t+1} published
  }
}

extern "C" void kernel_launch(void* const* d_in, const int* in_sizes, int n_in,
                              void* d_out, int out_size, void* d_ws, size_t ws_size,
                              hipStream_t stream)
{
  const float* enc    = (const float*)d_in[0];
  const float* mel    = (const float*)d_in[1];
  const int*   outlen = (const int*)d_in[3];
  const int*   cond   = (const int*)d_in[4];
  const float* Wih    = (const float*)d_in[5];
  const float* Whh    = (const float*)d_in[6];
  const float* bih    = (const float*)d_in[7];
  const float* bhh    = (const float*)d_in[8];
  const float* W1     = (const float*)d_in[9];
  const float* b1v    = (const float*)d_in[10];
  const float* W2     = (const float*)d_in[11];
  const float* Wlin   = (const float*)d_in[12];
  const float* blin   = (const float*)d_in[13];
  float* outp = (float*)d_out;
  float* wsf  = (float*)d_ws;

  (void)hipFuncSetAttribute((const void*)gmm_main,
                            hipFuncAttributeMaxDynamicSharedMemorySize,
                            (int)SMEM_BYTES);

  hipLaunchKernelGGL(gmm_init, dim3(64), dim3(256), 0, stream, wsf);

  void* args[] = {
    (void*)&enc, (void*)&mel, (void*)&outlen, (void*)&cond,
    (void*)&Wih, (void*)&Whh, (void*)&bih, (void*)&bhh,
    (void*)&W1, (void*)&b1v, (void*)&W2, (void*)&Wlin, (void*)&blin,
    (void*)&outp, (void*)&wsf
  };
  hipLaunchCooperativeKernel((void*)gmm_main, dim3(NBLK), dim3(NTHR),
                             args, SMEM_BYTES, stream);
}

// Round 5
// 60281.311 us; speedup vs baseline: 1.1140x; 1.1140x over previous
//
#include <hip/hip_runtime.h>
#include <stdint.h>

#define DEV static __device__ __forceinline__

namespace {
constexpr int Bx = 16, ENCx = 512, DECx = 800, Dx = 256, Hx = 1024;
constexpr int NBLK = 256, NTHR = 512;

// ---- workspace float offsets ----
constexpr int WS_HBUF = 0;                      // 2 * B*H (double-buffered h master, sc1)
constexpr int WS_CTX  = WS_HBUF + 2*Bx*Hx;      // B*D master
constexpr int WS_NCTX = WS_CTX  + Bx*Dx;        // B*D master
constexpr int WS_X1   = WS_NCTX + Bx*Dx;        // B*D master
constexpr int WS_AL   = WS_X1   + Bx*Dx;        // B*ENC master
constexpr int WS_XH   = WS_AL   + Bx*ENCx;      // 8 XCD * 16384 : per-XCD h scratch (plain)
constexpr int WS_XC   = WS_XH   + 8*Bx*Hx;      // 8 XCD * 8192  : per-XCD ctx|nctx scratch
constexpr int WS_FEND = WS_XC   + 8*2*Bx*Dx;
// ---- int offsets (relative to wsf + WS_FEND) ----
constexpr int IW_F1   = 0;                      // flag1[DEC]
constexpr int IW_F2   = IW_F1 + DECx;           // flag2[DEC*16]
constexpr int IW_SLOT = ((IW_F2 + DECx*16 + 63)/64)*64;
constexpr int IW_GEN  = IW_SLOT + 256 + 64;     // 8 replicated gen words, stride 32
constexpr int IW_EL1  = IW_GEN + 256;           // 8*16 election (bk>=64)
constexpr int IW_EL2  = IW_EL1 + 128;           // 8*16 fallback election
constexpr int IW_FH   = IW_EL2 + 128;           // 8*32 h-scratch ready flags (monotone t+1)
constexpr int IW_FC   = IW_FH + 256;            // 8*32 ctx-scratch ready flags
constexpr int IW_END  = IW_FC + 256;
constexpr size_t CTXOUT = (size_t)Bx*DECx*Dx;

// ---- dynamic LDS float offsets ----
constexpr int LH_STR = 1028;
constexpr int CT_STR = 260;
constexpr int LW_H   = 0;                       // 16*1028 h stage (reused as ctx|nctx 32*260)
constexpr int LW_WHH = LW_H + 16*LH_STR;        // 16384 Whh rows
constexpr int LW_TS  = LW_WHH + 16384;          // type-specific union
constexpr int TS_WLT = 0, TS_BLN = 6144, TS_X1L = 6168, TS_X2P = 6424, TS_X2L = 6936;
constexpr int TS_CPN = 0, TS_ALB = 1024;
constexpr int LDS_DYN_F = LW_TS + 7192;
constexpr size_t SMEM_BYTES = (size_t)LDS_DYN_F * 4;   // 160096 B
}

DEV float frcp(float x){ return __builtin_amdgcn_rcpf(x); }
DEV float sigm(float x){ return frcp(1.0f + __expf(-x)); }
DEV float ftanh(float x){
  x = fminf(fmaxf(x, -15.0f), 15.0f);
  float e = __expf(2.0f*x);
  return (e - 1.0f) * frcp(e + 1.0f);
}
DEV float wred16(float v){
  v += __shfl_xor(v, 1); v += __shfl_xor(v, 2);
  v += __shfl_xor(v, 4); v += __shfl_xor(v, 8);
  return v;
}
DEV int   ld_rlx(const int* p){ return __hip_atomic_load(p, __ATOMIC_RELAXED, __HIP_MEMORY_SCOPE_AGENT); }
DEV void  st_rlx(int* p, int v){ __hip_atomic_store(p, v, __ATOMIC_RELAXED, __HIP_MEMORY_SCOPE_AGENT); }
DEV float ldf_c(const float* p){ return __hip_atomic_load(p, __ATOMIC_RELAXED, __HIP_MEMORY_SCOPE_AGENT); }
DEV void  stf_c(float* p, float v){ __hip_atomic_store(p, v, __ATOMIC_RELAXED, __HIP_MEMORY_SCOPE_AGENT); }
DEV float2 ldf2_c(const float* p){
  unsigned long long u = __hip_atomic_load((const unsigned long long*)p,
                                           __ATOMIC_RELAXED, __HIP_MEMORY_SCOPE_AGENT);
  return __builtin_bit_cast(float2, u);
}
DEV void cbar(){ asm volatile("" ::: "memory"); }

DEV void spin_delay(){
  float x = 1.0f;
  #pragma unroll
  for (int i = 0; i < 24; ++i) x = fmaf(x, 1.0000001f, 1e-9f);
  asm volatile("" :: "v"(x));
}

// sc0-only loads: bypass L1, HIT the XCD-local L2 (where the leader's plain stores live).
DEV void ld128_sc0(float4 (&r)[8], const float* p){
  asm volatile(
    "global_load_dwordx4 %0, %8, off sc0\n\t"
    "global_load_dwordx4 %1, %8, off offset:512 sc0\n\t"
    "global_load_dwordx4 %2, %8, off offset:1024 sc0\n\t"
    "global_load_dwordx4 %3, %8, off offset:1536 sc0\n\t"
    "global_load_dwordx4 %4, %8, off offset:2048 sc0\n\t"
    "global_load_dwordx4 %5, %8, off offset:2560 sc0\n\t"
    "global_load_dwordx4 %6, %8, off offset:3072 sc0\n\t"
    "global_load_dwordx4 %7, %8, off offset:3584 sc0\n\t"
    "s_waitcnt vmcnt(0)"
    : "=&v"(r[0]), "=&v"(r[1]), "=&v"(r[2]), "=&v"(r[3]),
      "=&v"(r[4]), "=&v"(r[5]), "=&v"(r[6]), "=&v"(r[7])
    : "v"(p) : "memory");
}
DEV void ld64_sc0(float4 (&r)[4], const float* p){
  asm volatile(
    "global_load_dwordx4 %0, %4, off sc0\n\t"
    "global_load_dwordx4 %1, %4, off offset:256 sc0\n\t"
    "global_load_dwordx4 %2, %4, off offset:512 sc0\n\t"
    "global_load_dwordx4 %3, %4, off offset:768 sc0\n\t"
    "s_waitcnt vmcnt(0)"
    : "=&v"(r[0]), "=&v"(r[1]), "=&v"(r[2]), "=&v"(r[3])
    : "v"(p) : "memory");
}

DEV void flag_wait(int* p, int target){
  if (threadIdx.x == 0){
    while (ld_rlx(p) < target) spin_delay();
  }
  __syncthreads();
  cbar();
}

DEV void gridbar(int* slots, int* genp, unsigned &gen){
  const int next = (int)(gen + 1u);
  __syncthreads();                       // drains vmcnt: sc1 stores at coherence point
  if (threadIdx.x == 0) st_rlx(slots + blockIdx.x, next);
  if (blockIdx.x == 0 && threadIdx.x < 64){
    int* my = slots + threadIdx.x*4;
    for (;;){
      bool ok = (ld_rlx(my+0) >= next) & (ld_rlx(my+1) >= next) &
                (ld_rlx(my+2) >= next) & (ld_rlx(my+3) >= next);
      if (__ballot(ok) == ~0ull) break;
      spin_delay();
    }
    if (threadIdx.x < 8) st_rlx(genp + threadIdx.x*32, next);
  }
  if (threadIdx.x == 0){
    int* g = genp + (blockIdx.x & 7)*32;
    while (ld_rlx(g) < next) spin_delay();
  }
  __syncthreads();
  cbar();
  gen = (unsigned)next;
}

DEV void gchunk(float (&acc)[2][4], float4 wa, float4 wb, const float* xlane, size_t xstride, int b4){
  #pragma unroll
  for (int bi = 0; bi < 4; ++bi){
    float4 xv = *reinterpret_cast<const float4*>(xlane + (size_t)(b4*4 + bi)*xstride);
    acc[0][bi] = fmaf(wa.x,xv.x, fmaf(wa.y,xv.y, fmaf(wa.z,xv.z, fmaf(wa.w,xv.w, acc[0][bi]))));
    acc[1][bi] = fmaf(wb.x,xv.x, fmaf(wb.y,xv.y, fmaf(wb.z,xv.z, fmaf(wb.w,xv.w, acc[1][bi]))));
  }
}

extern "C" __global__ void gmm_init(float* wsf){
  int* wsi = (int*)(wsf + WS_FEND);
  int idx = blockIdx.x*blockDim.x + threadIdx.x;
  for (int k = idx; k < IW_END; k += gridDim.x*blockDim.x) wsi[k] = 0;
}

extern "C" __global__ void __launch_bounds__(NTHR, 1) gmm_main(
    const float* __restrict__ enc, const float* __restrict__ mel,
    const int* __restrict__ outlen, const int* __restrict__ condlen,
    const float* __restrict__ Wih, const float* __restrict__ Whh,
    const float* __restrict__ bih, const float* __restrict__ bhh,
    const float* __restrict__ W1,  const float* __restrict__ b1v,
    const float* __restrict__ W2,  const float* __restrict__ Wlin,
    const float* __restrict__ blin,
    float* __restrict__ out, float* __restrict__ wsf)
{
  const int bk = blockIdx.x, tid = threadIdx.x;
  const int lane = tid & 63;
  const int klane4 = (tid & 15) * 4;
  const int b4 = (tid >> 4) & 3;
  const int wid = tid >> 6;

  int* wsi   = (int*)(wsf + WS_FEND);
  int* flag1 = wsi + IW_F1;
  int* flag2 = wsi + IW_F2;
  int* slots = wsi + IW_SLOT;
  int* genp  = wsi + IW_GEN;
  int* el1   = wsi + IW_EL1;
  int* el2   = wsi + IW_EL2;
  int* flagH = wsi + IW_FH;
  int* flagC = wsi + IW_FC;
  float* hb0    = wsf + WS_HBUF;
  float* ctxws  = wsf + WS_CTX;
  float* nctxws = wsf + WS_NCTX;
  float* x1ws   = wsf + WS_X1;
  float* alws   = wsf + WS_AL;

  extern __shared__ float lds[];
  float* lh   = lds + LW_H;
  float* lwhh = lds + LW_WHH;
  float* lts  = lds + LW_TS;

  __shared__ float g_lds[256];
  __shared__ float bsum[16];
  __shared__ float cl[64];
  __shared__ float outl[32];
  __shared__ float mixw[8], mixlc[8], mixis[8];
  __shared__ float locl[8];
  __shared__ int   s_cond, s_olen;
  __shared__ int   s_xcd, s_lead;

  const int jidx0 = 2*wid;
  const int j0 = (jidx0 >> 2)*1024 + bk*4 + (jidx0 & 3);
  const int j1 = ((jidx0+1) >> 2)*1024 + bk*4 + ((jidx0+1) & 3);
  const float* WihR0 = Wih + (size_t)j0*768;   // read-only -> stays L2-resident (no fences ever)
  const float* WihR1 = Wih + (size_t)j1*768;

  const bool is_x1   = (bk < 32);
  const bool is_head = (bk >= 32 && bk < 48);
  const int  hbb     = bk - 32;

  int sl_cb = 0, sl_dc0 = 0, sl_n = 0;
  if (!is_head){
    int idx = (bk < 32) ? bk : (bk - 16);
    if (idx < 16){ sl_cb = idx; sl_dc0 = 14; sl_n = 2; }
    else { int j = idx - 16; sl_cb = j / 14; sl_dc0 = j % 14; sl_n = 1; }
  }

  // ---------------- XCD discovery + leader election (phase 1: bk>=64 only) ----------------
  if (tid == 0){
    int x;
    asm("s_getreg_b32 %0, hwreg(HW_REG_XCC_ID)" : "=s"(x));
    x &= 7;
    s_xcd = x;
    int lead = 0;
    if (bk >= 64){
      int old = __hip_atomic_fetch_add(el1 + x*16, 1, __ATOMIC_RELAXED, __HIP_MEMORY_SCOPE_AGENT);
      lead = (old == 0);
    }
    s_lead = lead;
  }
  __syncthreads();
  const int xcd = s_xcd;
  float* hscr = wsf + WS_XH + xcd*(Bx*Hx);      // per-XCD h scratch (plain stores, XCD L2)
  float* cscr = wsf + WS_XC + xcd*(2*Bx*Dx);    // per-XCD ctx|nctx scratch
  int* fH = flagH + xcd*32;
  int* fC = flagC + xcd*32;

  // ---------------- one-time staging ----------------
  #pragma unroll
  for (int jj = jidx0; jj <= jidx0 + 1; ++jj){
    const int gj = (jj >> 2)*1024 + bk*4 + (jj & 3);
    float4* dst = (float4*)(lwhh + jj*1024);
    const float4* s = (const float4*)(Whh + (size_t)gj*1024);
    for (int i = lane; i < 256; i += 64) dst[i] = s[i];
  }
  if (tid < 16){
    int g = tid >> 2, ul = tid & 3, u = bk*4 + ul;
    bsum[tid] = bih[g*1024 + u] + bhh[g*1024 + u];
  }
  float4 w2r[32];
  if (is_head){
    for (int i = tid; i < 6144; i += NTHR){
      int k = i / 24, r = i % 24;
      lts[TS_WLT + i] = Wlin[(size_t)r*256 + k];
    }
    if (tid < 24) lts[TS_BLN + tid] = blin[tid];
    if (tid == 0){ s_cond = condlen[hbb]; s_olen = outlen[hbb]; }
    if (tid < 8) locl[tid] = -0.1f;
    {
      int r = tid >> 1, hf = tid & 1;
      const float* w2row = W2 + (size_t)r*256 + hf*128;
      #pragma unroll
      for (int i = 0; i < 32; ++i) w2r[i] = *reinterpret_cast<const float4*>(w2row + i*4);
    }
  }
  __syncthreads();

  auto ctx_slice = [&](int cb, int dc, int t){
    int d0 = dc * 16;
    int dl = tid & 15, eg = tid >> 4;
    int d = d0 + dl;
    const float* encb = enc + (size_t)cb*ENCx*Dx;
    const float* albl = lts + TS_ALB;
    float* cpn = lts + TS_CPN;
    float ca = 0.f, na = 0.f;
    #pragma unroll
    for (int i = 0; i < 16; ++i){
      int e = eg*16 + i;
      float av = albl[e];
      float nv = albl[(e + 511) & 511];
      float ev = encb[(size_t)e*256 + d];
      ca = fmaf(av, ev, ca);
      na = fmaf(nv, ev, na);
    }
    cpn[0*512 + eg*16 + dl] = ca;
    cpn[1*512 + eg*16 + dl] = na;
    __syncthreads();
    if (tid < 32){
      int z = tid >> 4, dd = tid & 15;
      float sum = 0.f;
      #pragma unroll
      for (int g2 = 0; g2 < 32; ++g2) sum += cpn[z*512 + g2*16 + dd];
      if (z == 0){
        stf_c(ctxws + cb*256 + d0 + dd, sum);
        out[(size_t)cb*((size_t)DECx*Dx) + (size_t)t*Dx + d0 + dd] = sum;
      } else {
        stf_c(nctxws + cb*256 + d0 + dd, sum);
      }
    }
    __syncthreads();
  };

  unsigned gen = 0;

  // ---------------- prologue: gates t=0 (q=[mel0, 0, enc[:,0,:]], h=0, c=0) ----------------
  {
    float acc[2][4] = {{0,0,0,0},{0,0,0,0}};
    #pragma unroll
    for (int it = 0; it < 4; ++it){
      int k = it*64 + klane4;
      gchunk(acc, *(const float4*)(WihR0 + k), *(const float4*)(WihR1 + k),
             mel + k, (size_t)DECx*Dx, b4);
    }
    #pragma unroll
    for (int it = 0; it < 4; ++it){
      int k = it*64 + klane4;
      gchunk(acc, *(const float4*)(WihR0 + 512 + k), *(const float4*)(WihR1 + 512 + k),
             enc + k, (size_t)ENCx*Dx, b4);
    }
    #pragma unroll
    for (int jj = 0; jj < 2; ++jj)
      #pragma unroll
      for (int bi = 0; bi < 4; ++bi){
        float v = wred16(acc[jj][bi]);
        if ((tid & 15) == 0) g_lds[(jidx0 + jj)*16 + b4*4 + bi] = v;
      }
    __syncthreads();
    if (tid < 64){
      int b = tid & 15, ul = tid >> 4, u = bk*4 + ul;
      float gi = g_lds[( 0 + ul)*16 + b] + bsum[ul];
      float gg = g_lds[( 8 + ul)*16 + b] + bsum[8 + ul];
      float go = g_lds[(12 + ul)*16 + b] + bsum[12 + ul];
      float c2 = sigm(gi) * ftanh(gg);
      float h2 = sigm(go) * ftanh(c2);
      cl[b*4 + ul] = c2;
      stf_c(hb0 + b*1024 + u, h2);
    }
  }
  gridbar(slots, genp, gen);   // also finalizes phase-1 election counts

  // ---------------- leader election phase 2 (fallback if XCD had no bk>=64 block) ----------------
  if (tid == 0 && !s_lead){
    if (ld_rlx(el1 + xcd*16) == 0){
      int old = __hip_atomic_fetch_add(el2 + xcd*16, 1, __ATOMIC_RELAXED, __HIP_MEMORY_SCOPE_AGENT);
      if (old == 0) s_lead = 1;
    }
  }
  __syncthreads();
  const bool lead = (s_lead != 0);

  // ---------------- main loop ----------------
  for (int t = 0; t < DECx; ++t){
    // ---- leader: master h (sc1) -> per-XCD scratch (plain -> XCD L2), publish flag
    if (lead){
      const float* hsrc = hb0 + (t & 1)*(Bx*Hx);
      #pragma unroll
      for (int i = 0; i < 16; ++i){
        int j = tid + i*512;                       // float2 index
        *reinterpret_cast<float2*>(hscr + 2*j) = ldf2_c(hsrc + 2*j);
      }
      __syncthreads();                              // vmcnt(0): scratch in L2
      if (tid == 0) st_rlx(fH, t + 1);
    }

    // ---- region 1a: mel gate partial (no h needed; hides leader-copy latency)
    float acc[2][4] = {{0,0,0,0},{0,0,0,0}};
    if (t < DECx - 1){
      const int tt = t + 1;
      #pragma unroll
      for (int it = 0; it < 4; ++it){
        int k = it*64 + klane4;
        gchunk(acc, *(const float4*)(WihR0 + k), *(const float4*)(WihR1 + k),
               mel + (size_t)tt*Dx + k, (size_t)DECx*Dx, b4);
      }
    }

    // ---- wait h ready; stage scratch -> LDS via sc0 (L2-hit) loads
    if (tid == 0){ while (ld_rlx(fH) < t + 1) spin_delay(); }
    __syncthreads();
    cbar();
    {
      const float* hs = hscr + (tid >> 5)*1024 + (tid & 31)*4;
      float4 r[8];
      ld128_sc0(r, hs);
      float* dst = lh + (tid >> 5)*LH_STR + (tid & 31)*4;
      #pragma unroll
      for (int i = 0; i < 8; ++i) *reinterpret_cast<float4*>(dst + 128*i) = r[i];
    }
    __syncthreads();

    // ---- x1 engines (h from LDS, W1 from L2)
    if (is_x1){
      int d = bk*8 + wid;
      const float* W1r = W1 + (size_t)d*1024;
      float a4[4] = {0,0,0,0};
      #pragma unroll 4
      for (int it = 0; it < 16; ++it){
        int k = it*64 + klane4;
        float4 wq = *(const float4*)(W1r + k);
        #pragma unroll
        for (int bi = 0; bi < 4; ++bi){
          float4 xv = *(const float4*)(lh + (size_t)(b4*4 + bi)*LH_STR + k);
          a4[bi] = fmaf(wq.x,xv.x, fmaf(wq.y,xv.y, fmaf(wq.z,xv.z, fmaf(wq.w,xv.w, a4[bi]))));
        }
      }
      #pragma unroll
      for (int bi = 0; bi < 4; ++bi){
        float v = wred16(a4[bi]);
        if ((tid & 15) == 0){
          v += b1v[d];
          v = (v >= 0.f) ? v : 0.1f*v;
          stf_c(x1ws + (b4*4 + bi)*256 + d, v);
        }
      }
      __syncthreads();
      if (tid == 0)
        __hip_atomic_fetch_add(flag1 + t, 1, __ATOMIC_RELAXED, __HIP_MEMORY_SCOPE_AGENT);
    }

    // ---- head engines (one block per batch): x2 -> out -> softmax -> align
    if (is_head){
      flag_wait(flag1 + t, 32);
      if (tid < 256) lts[TS_X1L + tid] = ldf_c(x1ws + hbb*256 + tid);
      __syncthreads();
      {
        int hf = tid & 1;
        const float* x1b = lts + TS_X1L + hf*128;
        float a = 0.f;
        #pragma unroll
        for (int i = 0; i < 32; ++i){
          float4 xv = *(const float4*)(x1b + i*4);
          a = fmaf(w2r[i].x,xv.x, fmaf(w2r[i].y,xv.y, fmaf(w2r[i].z,xv.z, fmaf(w2r[i].w,xv.w, a))));
        }
        lts[TS_X2P + tid] = a;
      }
      __syncthreads();
      if (tid < 256) lts[TS_X2L + tid] = ftanh(lts[TS_X2P + 2*tid] + lts[TS_X2P + 2*tid + 1]);
      __syncthreads();
      if (tid < 24){
        float s = lts[TS_BLN + tid];
        #pragma unroll 8
        for (int k = 0; k < 256; ++k) s = fmaf(lts[TS_X2L + k], lts[TS_WLT + k*24 + tid], s);
        outl[tid] = s;
      }
      __syncthreads();
      if (tid == 0){
        float w8[8]; float mx = -1e30f;
        #pragma unroll
        for (int m = 0; m < 8; ++m){ w8[m] = outl[m]; mx = fmaxf(mx, w8[m]); }
        float sum = 0.f;
        #pragma unroll
        for (int m = 0; m < 8; ++m){ w8[m] = __expf(w8[m] - mx); sum += w8[m]; }
        float inv = frcp(sum);
        float cm1 = (float)s_cond - 1.0f;
        #pragma unroll
        for (int m = 0; m < 8; ++m){
          mixw[m] = w8[m] * inv;
          float dl = sigm(outl[8 + m]) + 0.005f;
          float lc = locl[m] + dl;
          mixlc[m] = lc;
          locl[m]  = fminf(lc, cm1);
          mixis[m] = 1.0f + __expf(-outl[16 + m]);
        }
      }
      __syncthreads();
      {
        float e = (float)tid;
        float a = 0.f;
        #pragma unroll
        for (int m = 0; m < 8; ++m){
          float df = mixlc[m] - e;
          a += (ftanh((df + 0.5f)*mixis[m]) - ftanh((df - 0.5f)*mixis[m])) * mixw[m];
        }
        a *= 0.5f;
        bool valid = (tid < s_cond) && (t < s_olen);
        if (!valid) a = 0.f;
        stf_c(alws + hbb*512 + tid, a);
        out[CTXOUT + (size_t)hbb*((size_t)DECx*ENCx) + (size_t)t*ENCx + tid] = a;
      }
      __syncthreads();
      if (tid == 0) st_rlx(flag2 + t*16 + hbb, 1);
    }

    // ---- region 1b: Whh * h gate partial (Whh + h both in LDS)
    if (t < DECx - 1){
      #pragma unroll 4
      for (int it = 0; it < 16; ++it){
        int k = it*64 + klane4;
        gchunk(acc, *(const float4*)(lwhh + jidx0*1024 + k), *(const float4*)(lwhh + (jidx0+1)*1024 + k),
               lh + k, LH_STR, b4);
      }
    }

    // ---- ctx duty (head exempt)
    if (!is_head){
      flag_wait(flag2 + t*16 + sl_cb, 1);
      lts[TS_ALB + tid] = ldf_c(alws + sl_cb*512 + tid);
      __syncthreads();
      ctx_slice(sl_cb, sl_dc0, t);
      if (sl_n == 2) ctx_slice(sl_cb, sl_dc0 + 1, t);
    }

    gridbar(slots, genp, gen);   // barrier A: ctx/nctx master published

    // ---- region 2: ctx/nctx gate part + LSTM cell -> h_{t+1}
    if (t < DECx - 1){
      // leader: ctx|nctx master (sc1) -> per-XCD scratch, flag
      if (lead){
        #pragma unroll
        for (int i = 0; i < 4; ++i){
          int j = tid + i*512;                     // float2 index, 2048 per array
          *reinterpret_cast<float2*>(cscr + 2*j)        = ldf2_c(ctxws + 2*j);
          *reinterpret_cast<float2*>(cscr + 4096 + 2*j) = ldf2_c(nctxws + 2*j);
        }
        __syncthreads();
        if (tid == 0) st_rlx(fC, t + 1);
      }
      if (tid == 0){ while (ld_rlx(fC) < t + 1) spin_delay(); }
      __syncthreads();
      cbar();
      {
        const float* cs = cscr + (tid >> 4)*256 + (tid & 15)*4;
        float4 r[4];
        ld64_sc0(r, cs);
        float* dst = lh + (tid >> 4)*CT_STR + (tid & 15)*4;
        #pragma unroll
        for (int i = 0; i < 4; ++i) *reinterpret_cast<float4*>(dst + 64*i) = r[i];
      }
      __syncthreads();
      #pragma unroll
      for (int it = 0; it < 4; ++it){
        int k = it*64 + klane4;
        gchunk(acc, *(const float4*)(WihR0 + 256 + k), *(const float4*)(WihR1 + 256 + k),
               lh + k, CT_STR, b4);
      }
      #pragma unroll
      for (int it = 0; it < 4; ++it){
        int k = it*64 + klane4;
        gchunk(acc, *(const float4*)(WihR0 + 512 + k), *(const float4*)(WihR1 + 512 + k),
               lh + 16*CT_STR + k, CT_STR, b4);
      }
      #pragma unroll
      for (int jj = 0; jj < 2; ++jj)
        #pragma unroll
        for (int bi = 0; bi < 4; ++bi){
          float v = wred16(acc[jj][bi]);
          if ((tid & 15) == 0) g_lds[(jidx0 + jj)*16 + b4*4 + bi] = v;
        }
      __syncthreads();
      if (tid < 64){
        int b = tid & 15, ul = tid >> 4, u = bk*4 + ul;
        float gi = g_lds[( 0 + ul)*16 + b] + bsum[ul];
        float gf = g_lds[( 4 + ul)*16 + b] + bsum[4 + ul];
        float gg = g_lds[( 8 + ul)*16 + b] + bsum[8 + ul];
        float go = g_lds[(12 + ul)*16 + b] + bsum[12 + ul];
        float co = cl[b*4 + ul];
        float c2 = sigm(gf)*co + sigm(gi)*ftanh(gg);
        float h2 = sigm(go)*ftanh(c2);
        cl[b*4 + ul] = c2;
        stf_c(hb0 + ((t + 1) & 1)*(Bx*Hx) + b*1024 + u, h2);
      }
    }

    gridbar(slots, genp, gen);   // barrier B: h_{t+1} master published
  }
}

extern "C" void kernel_launch(void* const* d_in, const int* in_sizes, int n_in,
                              void* d_out, int out_size, void* d_ws, size_t ws_size,
                              hipStream_t stream)
{
  const float* enc    = (const float*)d_in[0];
  const float* mel    = (const float*)d_in[1];
  const int*   outlen = (const int*)d_in[3];
  const int*   cond   = (const int*)d_in[4];
  const float* Wih    = (const float*)d_in[5];
  const float* Whh    = (const float*)d_in[6];
  const float* bih    = (const float*)d_in[7];
  const float* bhh    = (const float*)d_in[8];
  const float* W1     = (const float*)d_in[9];
  const float* b1v    = (const float*)d_in[10];
  const float* W2     = (const float*)d_in[11];
  const float* Wlin   = (const float*)d_in[12];
  const float* blin   = (const float*)d_in[13];
  float* outp = (float*)d_out;
  float* wsf  = (float*)d_ws;

  (void)hipFuncSetAttribute((const void*)gmm_main,
                            hipFuncAttributeMaxDynamicSharedMemorySize,
                            (int)SMEM_BYTES);

  hipLaunchKernelGGL(gmm_init, dim3(64), dim3(256), 0, stream, wsf);

  void* args[] = {
    (void*)&enc, (void*)&mel, (void*)&outlen, (void*)&cond,
    (void*)&Wih, (void*)&Whh, (void*)&bih, (void*)&bhh,
    (void*)&W1, (void*)&b1v, (void*)&W2, (void*)&Wlin, (void*)&blin,
    (void*)&outp, (void*)&wsf
  };
  hipLaunchCooperativeKernel((void*)gmm_main, dim3(NBLK), dim3(NTHR),
                             args, SMEM_BYTES, stream);
}